// Round 3
// 3525.853 us; speedup vs baseline: 1.8520x; 1.8520x over previous
//
#include <hip/hip_runtime.h>
#include <math.h>

typedef _Float16 half8 __attribute__((ext_vector_type(8)));
typedef _Float16 half4 __attribute__((ext_vector_type(4)));
typedef float floatx4 __attribute__((ext_vector_type(4)));
typedef unsigned long long u64;

#define NB 64
#define LQ 512
#define HD 1024

__device__ inline half8 cvt2(const float4 a, const float4 b) {
  half8 h;
  h[0]=(_Float16)a.x; h[1]=(_Float16)a.y; h[2]=(_Float16)a.z; h[3]=(_Float16)a.w;
  h[4]=(_Float16)b.x; h[5]=(_Float16)b.y; h[6]=(_Float16)b.z; h[7]=(_Float16)b.w;
  return h;
}

// System-scope (sc0 sc1) accessors: bypass L1+L2, coherent at IF$.
// NOTE: operands must be ext_vector types (HIP float4 is a struct and cannot
// lower to a "v" asm constraint).
__device__ inline floatx4 ld_sc16(const void* p) {
  floatx4 r;
  asm volatile("global_load_dwordx4 %0, %1, off sc0 sc1"
               : "=v"(r) : "v"(p) : "memory");
  return r;
}
__device__ inline void st_sc16(void* p, floatx4 v) {
  asm volatile("global_store_dwordx4 %0, %1, off sc0 sc1"
               :: "v"(p), "v"(v) : "memory");
}
__device__ inline void st_flag(int* p, int v) {
  __hip_atomic_store(p, v, __ATOMIC_RELAXED, __HIP_MEMORY_SCOPE_SYSTEM);
}
__device__ inline void vmcnt0() { asm volatile("s_waitcnt vmcnt(0)" ::: "memory"); }

// Fast tanh: 1 - 2/(e^{2x}+1). exp overflow/underflow saturate correctly.
__device__ inline float ftanh(float x) {
  float e = __expf(2.0f * x);
  return 1.0f - 2.0f / (e + 1.0f);
}

// ---------------------------------------------------------------------------
// GEMM1 (unchanged, verified): out[m][o] = emb[x[m]].Wxh[o] + bxh[o]+bhh[o]
// ---------------------------------------------------------------------------
__global__ __launch_bounds__(256) void gemm1_kernel(
    const int* __restrict__ x, const float* __restrict__ emb,
    const float* __restrict__ Wxh, const float* __restrict__ bxh,
    const float* __restrict__ bhh, float* __restrict__ out)
{
  __shared__ alignas(16) _Float16 As[128][72];
  __shared__ alignas(16) _Float16 Bs[128][72];
  const int tid  = threadIdx.x;
  const int lane = tid & 63, wv = tid >> 6;
  const int wm = wv & 1, wn = wv >> 1;
  const int Mbase = blockIdx.x * 128;
  const int Nbase = blockIdx.y * 128;

  const int srow  = tid >> 1;
  const int shalf = tid & 1;
  const size_t erow = (size_t)x[Mbase + srow] * HD;
  const size_t brow = (size_t)(Nbase + srow) * HD;

  floatx4 acc[4][4];
#pragma unroll
  for (int i = 0; i < 4; i++)
#pragma unroll
    for (int j = 0; j < 4; j++) acc[i][j] = (floatx4)0.f;

  for (int c = 0; c < 16; ++c) {
    const int k0 = c * 64 + shalf * 32;
    const float4* ap = (const float4*)(emb + erow + k0);
    const float4* bp = (const float4*)(Wxh + brow + k0);
    float4 av[8], bv[8];
#pragma unroll
    for (int i = 0; i < 8; i++) { av[i] = ap[i]; bv[i] = bp[i]; }
    __syncthreads();
#pragma unroll
    for (int i = 0; i < 4; i++) {
      *(half8*)&As[srow][shalf*32 + i*8] = cvt2(av[2*i], av[2*i+1]);
      *(half8*)&Bs[srow][shalf*32 + i*8] = cvt2(bv[2*i], bv[2*i+1]);
    }
    __syncthreads();
#pragma unroll
    for (int s = 0; s < 2; ++s) {
      const int koff = s*32 + (lane >> 4) * 8;
      half8 af[4], bf[4];
#pragma unroll
      for (int i = 0; i < 4; i++) {
        af[i] = *(const half8*)&As[wm*64 + i*16 + (lane & 15)][koff];
        bf[i] = *(const half8*)&Bs[wn*64 + i*16 + (lane & 15)][koff];
      }
#pragma unroll
      for (int i = 0; i < 4; i++)
#pragma unroll
        for (int j = 0; j < 4; j++)
          acc[i][j] = __builtin_amdgcn_mfma_f32_16x16x32_f16(af[i], bf[j], acc[i][j], 0, 0, 0);
    }
  }
#pragma unroll
  for (int j = 0; j < 4; j++) {
    const int o = Nbase + wn*64 + j*16 + (lane & 15);
    const float bias = bxh[o] + bhh[o];
#pragma unroll
    for (int i = 0; i < 4; i++) {
      const int mb = Mbase + wm*64 + i*16 + ((lane >> 4) * 4);
#pragma unroll
      for (int r = 0; r < 4; r++)
        out[(size_t)(mb + r) * HD + o] = acc[i][j][r] + bias;
    }
  }
}

// ---------------------------------------------------------------------------
// RNN v3: operand-swapped MFMA (D = W·h) so batch sits on C-layout "col".
// Producer publishes h in CONSUMER FRAGMENT ORDER: per-wave LDS transpose
// (16x40 f16, no barriers) then ONE coalesced dwordx4 sc0sc1 store (1 KB).
// Consumer: one 8B poll load covering all 128 flags, then 32 fully-coalesced
// dwordx4 sc0sc1 loads (1 KB each), split vmcnt(16)/vmcnt(0) feeding 4
// independent MFMA chains of depth 16. out[] stores after flag publish.
// ---------------------------------------------------------------------------
__global__ __launch_bounds__(256, 1) void rnn_kernel(
    const float* __restrict__ Whh, float* __restrict__ out,
    char* __restrict__ hb, int* __restrict__ flags)
{
  __shared__ alignas(16) _Float16 Ws[32 * 1024];     // 64 KB W_hh slice (f16, swizzled)
  __shared__ alignas(16) _Float16 Tls[4 * 16 * 40];  // 5 KB per-wave transpose tiles
  const int tid = threadIdx.x, lane = tid & 63, w = tid >> 6;
  const int j = blockIdx.x, obase = j * 32;
  const int col = lane & 15, quad = lane >> 4;
  const int wid = j * 4 + w;                          // per-wave flag id 0..127

  // ---- stage W_hh slice fp32 -> f16, swizzled (unchanged, verified)
  {
    const int o = tid >> 3, t8 = tid & 7;
    const float* src = Whh + (size_t)(obase + o) * HD;
#pragma unroll
    for (int i = 0; i < 16; ++i) {
      const int c16 = t8 * 16 + i;
      float4 v0 = *(const float4*)(src + c16 * 8);
      float4 v1 = *(const float4*)(src + c16 * 8 + 4);
      *(half8*)&Ws[o * 1024 + ((c16 ^ (o & 7)) * 8)] = cvt2(v0, v1);
    }
  }
  __syncthreads();                                    // only barrier in the kernel

  const int n = 16 * w + col;                         // this lane's batch row
  _Float16* Tw = &Tls[w * 640];                       // wave-private 16x40 tile
  float* outp = out + (size_t)n * LQ * HD + obase + quad * 4;
  u64* fl64 = (u64*)flags;
  char* hbw = hb + (size_t)w * 32768 + (size_t)lane * 16;

  for (int t = 0; t < LQ; ++t) {
    // xh prefetch: own channels, contiguous float4 (overlaps the poll below)
    const float* xp = outp + (size_t)t * HD;
    floatx4 xv0 = *(const floatx4*)xp;
    floatx4 xv1 = *(const floatx4*)(xp + 16);
    floatx4 acc0 = (floatx4)0.f, acc1 = (floatx4)0.f;

    if (t > 0) {
      // ---- wait for all 128 waves at step >= t (poison = negative)
      int spins = 0;
      for (;;) {
        u64 v = __hip_atomic_load(&fl64[lane], __ATOMIC_RELAXED, __HIP_MEMORY_SCOPE_SYSTEM);
        int lo = (int)(unsigned)v, hi = (int)(v >> 32);
        if (__all(lo >= t && hi >= t)) break;
        if (++spins > (1 << 20)) break;               // wrong > hung
      }

      // ---- h_{t-1} B-fragments: 32 coalesced 1 KB loads from IF$
      const char* blk = hbw + (size_t)((t - 1) & 1) * 131072;
      floatx4 hv[32];
#pragma unroll
      for (int c = 0; c < 32; ++c) hv[c] = ld_sc16(blk + c * 1024);

      floatx4 a0a = (floatx4)0.f, a1a = (floatx4)0.f;
      floatx4 a0b = (floatx4)0.f, a1b = (floatx4)0.f;
      asm volatile("s_waitcnt vmcnt(16)" ::: "memory"); // first 16 blocks landed
      __builtin_amdgcn_sched_barrier(0);
#pragma unroll
      for (int c = 0; c < 16; ++c) {
        const int sw = ((4 * c + quad) ^ (col & 7)) * 8;
        half8 b0 = *(const half8*)&Ws[col * 1024 + sw];
        half8 b1 = *(const half8*)&Ws[(16 + col) * 1024 + sw];
        half8 hf = __builtin_bit_cast(half8, hv[c]);
        a0a = __builtin_amdgcn_mfma_f32_16x16x32_f16(b0, hf, a0a, 0, 0, 0);
        a1a = __builtin_amdgcn_mfma_f32_16x16x32_f16(b1, hf, a1a, 0, 0, 0);
      }
      vmcnt0();                                        // rest of the blocks
      __builtin_amdgcn_sched_barrier(0);
#pragma unroll
      for (int c = 16; c < 32; ++c) {
        const int sw = ((4 * c + quad) ^ (col & 7)) * 8;
        half8 b0 = *(const half8*)&Ws[col * 1024 + sw];
        half8 b1 = *(const half8*)&Ws[(16 + col) * 1024 + sw];
        half8 hf = __builtin_bit_cast(half8, hv[c]);
        a0b = __builtin_amdgcn_mfma_f32_16x16x32_f16(b0, hf, a0b, 0, 0, 0);
        a1b = __builtin_amdgcn_mfma_f32_16x16x32_f16(b1, hf, a1b, 0, 0, 0);
      }
      acc0 = a0a + a0b;
      acc1 = a1a + a1b;
    }

    // ---- h = tanh(acc + xh); channels are contiguous per lane now
    floatx4 h0, h1;
    half4 p0, p1;
#pragma unroll
    for (int r = 0; r < 4; ++r) {
      h0[r] = ftanh(acc0[r] + xv0[r]);
      h1[r] = ftanh(acc1[r] + xv1[r]);
      p0[r] = (_Float16)h0[r];
      p1[r] = (_Float16)h1[r];
    }

    // ---- in-wave transpose to consumer fragment order (wave-private tile)
    *(half4*)&Tw[col * 40 + quad * 4] = p0;            // k' = quad*4 + r
    *(half4*)&Tw[col * 40 + 16 + quad * 4] = p1;       // k' = 16 + quad*4 + r
    __builtin_amdgcn_wave_barrier();
    asm volatile("s_waitcnt lgkmcnt(0)" ::: "memory");
    floatx4 myc = *(const floatx4*)&Tw[col * 40 + quad * 8];

    // ---- publish: ONE coalesced 1 KB store per wave, drain, flag
    st_sc16(hb + (size_t)(t & 1) * 131072 + (size_t)w * 32768 +
            (size_t)j * 1024 + (size_t)lane * 16, myc);
    vmcnt0();                                          // h at IF$ before publish
    if (lane == 0) st_flag(&flags[wid], t + 1);

    // ---- out stores AFTER flag publish: off the critical path
    float* op = outp + (size_t)t * HD;
    *(floatx4*)op = h0;
    *(floatx4*)(op + 16) = h1;
  }
}

extern "C" void kernel_launch(void* const* d_in, const int* in_sizes, int n_in,
                              void* d_out, int out_size, void* d_ws, size_t ws_size,
                              hipStream_t stream) {
  const int*   x   = (const int*)d_in[0];
  const float* emb = (const float*)d_in[1];
  const float* Whh = (const float*)d_in[2];
  const float* bhh = (const float*)d_in[3];
  const float* Wxh = (const float*)d_in[4];
  const float* bxh = (const float*)d_in[5];
  float* out = (float*)d_out;

  char* hbuf = (char*)d_ws;                            // 2 x 128 KB fragment buffers
  int*  fl   = (int*)((char*)d_ws + 262144);           // 128 per-wave flags

  gemm1_kernel<<<dim3(256, 8), 256, 0, stream>>>(x, emb, Wxh, bxh, bhh, out);
  rnn_kernel<<<dim3(32), 256, 0, stream>>>(Whh, out, hbuf, fl);
}